// Round 4
// baseline (550.497 us; speedup 1.0000x reference)
//
#include <hip/hip_runtime.h>
#include <stdint.h>

// Problem constants (f32 world)
#define R_ 8
#define B_ 8
#define L_ 4096
#define D_ 128
#define C_ 64             // N_HASHES
#define ROWS_BL 32768     // B_*L_
// d_out: f32 elements [x_sorted 33,554,432][sorted_hashes 262,144][sorted_indices 262,144]
#define XS_ELEMS 33554432
#define HS_ELEMS 262144

// Kernel 1: per (row, r): f64 norm, f64 normalized dots vs 64 hyperplanes,
// first-wins argmax over [rot, -rot]. Raw hash (0..127) -> d_ws u16 table.
__global__ __launch_bounds__(256) void khash(const float* __restrict__ x,
                                             const float* __restrict__ rm,
                                             uint16_t* __restrict__ hws) {
    int row = blockIdx.x * 256 + threadIdx.x;   // (b,l), 0..32767
    int r = blockIdx.y;
    const float* xr = x + (size_t)row * D_;

    // f64 norm (faithful order; ulp-level order effects are irrelevant vs gaps)
    double s = 0.0;
    double n0 = 0.0, n1 = 0.0, n2 = 0.0, n3 = 0.0;
#pragma unroll
    for (int d = 0; d < D_; d += 4) {
        double v0 = (double)xr[d+0], v1 = (double)xr[d+1];
        double v2 = (double)xr[d+2], v3 = (double)xr[d+3];
        n0 = fma(v0, v0, n0); n1 = fma(v1, v1, n1);
        n2 = fma(v2, v2, n2); n3 = fma(v3, v3, n3);
    }
    s = (n0 + n1) + (n2 + n3);
    double norm = sqrt(s);
    if (norm < 1e-12) norm = 1e-12;
    double rinv = 1.0 / norm;

    const float* w = rm + (size_t)r * (C_ * D_);   // [c][d], wave-uniform reads
    double acc[C_];
#pragma unroll
    for (int c = 0; c < C_; ++c) acc[c] = 0.0;

    for (int chunk = 0; chunk < 4; ++chunk) {      // d in chunks of 32
        double q[32];
        const float* xc = xr + chunk * 32;
#pragma unroll
        for (int j = 0; j < 32; ++j) q[j] = (double)xc[j] * rinv;
        const float* wc0 = w + chunk * 32;
        for (int c = 0; c < C_; ++c) {
            const float* wc = wc0 + c * D_;
            double a0 = 0.0, a1 = 0.0, a2 = 0.0, a3 = 0.0;
#pragma unroll
            for (int j = 0; j < 32; j += 4) {
                a0 = fma(q[j+0], (double)wc[j+0], a0);
                a1 = fma(q[j+1], (double)wc[j+1], a1);
                a2 = fma(q[j+2], (double)wc[j+2], a2);
                a3 = fma(q[j+3], (double)wc[j+3], a3);
            }
            acc[c] += ((a0 + a1) + (a2 + a3));
        }
    }

    double bp = -1e300, bn = -1e300;
    int bpi = 0, bni = 0;
#pragma unroll
    for (int c = 0; c < C_; ++c) {
        double v = acc[c];
        if (v > bp) { bp = v; bpi = c; }     // first-wins on + side
        if (-v > bn) { bn = -v; bni = c; }   // first-wins on - side
    }
    int idx = (bp >= bn) ? bpi : (C_ + bni); // concat order: + side first
    hws[((size_t)r << 15) + row] = (uint16_t)idx;   // [rb*4096 + l]
}

// Kernel 2: stable counting sort per (r,b). Reads its OWN 4096-u16 ws slice,
// writes f32 sorted_hashes / sorted_indices, then overwrites the same ws
// slice with the dest->src permutation (block-local; race-free).
__global__ __launch_bounds__(256) void ksort(uint16_t* __restrict__ hws,
                                             float* __restrict__ out) {
    int rb = blockIdx.x;          // r*8+b, 0..63
    int t = threadIdx.x;
    __shared__ uint16_t h[4096];
    __shared__ uint16_t cnt[64 * 128];   // [chunk][bin]
    __shared__ uint16_t inv[4096];       // dest -> src pos
    __shared__ int base[128];
    uint16_t* slice = hws + ((size_t)rb << 12);   // own 4096 u16
    for (int i = t; i < 4096; i += 256) h[i] = slice[i];
    for (int i = t; i < 8192; i += 256) cnt[i] = 0;
    __syncthreads();
    if (t < 64) {                         // per-chunk histogram (chunk = 64 pos)
        uint16_t* c = cnt + (t << 7);
        const uint16_t* hh = h + (t << 6);
        for (int i = 0; i < 64; ++i) c[hh[i] & 127]++;
    }
    __syncthreads();
    if (t < 128) {                        // exclusive prefix over chunks, per bin
        int run = 0;
        for (int ch = 0; ch < 64; ++ch) {
            int v = cnt[(ch << 7) + t];
            cnt[(ch << 7) + t] = (uint16_t)run;
            run += v;
        }
        base[t] = run;                    // bin totals (temporarily)
    }
    __syncthreads();
    if (t == 0) {                         // bin base offsets
        int run = 0;
        for (int bin = 0; bin < 128; ++bin) { int v = base[bin]; base[bin] = run; run += v; }
    }
    __syncthreads();
    if (t < 64) {                         // stable scatter
        uint16_t* c = cnt + (t << 7);
        const uint16_t* hh = h + (t << 6);
        int p0 = t << 6;
        for (int i = 0; i < 64; ++i) {
            int bin = hh[i] & 127;
            int dest = base[bin] + c[bin];
            c[bin]++;
            inv[dest] = (uint16_t)(p0 + i);
        }
    }
    __syncthreads();
    float* out_h = out + XS_ELEMS;
    float* out_i = out + XS_ELEMS + HS_ELEMS;
    int obase = rb << 12;
    for (int dst = t; dst < 4096; dst += 256) {
        int p = inv[dst];
        out_h[obase + dst] = (float)((h[p] & 127) + 1);   // 1..128, exact in f32
        out_i[obase + dst] = (float)p;                    // 0..4095, exact in f32
        slice[dst] = (uint16_t)p;                         // in-place inv for kgather
    }
}

// Kernel 3: gather x rows (f32 bit-exact). One float4 (16B) per thread;
// 32 threads cover one 512B row. Total float4 = XS_ELEMS/4 = 8,388,608.
__global__ void kgather(const float* __restrict__ x,
                        const uint16_t* __restrict__ inv,
                        float4* __restrict__ outx) {
    int id = blockIdx.x * 256 + threadIdx.x;   // float4 units
    int lane = id & 31;                        // 16B lane within 512B row
    int rowg = id >> 5;                        // rb*4096 + dst, 0..262143
    int b = (rowg >> 12) & 7;
    int src = inv[rowg] & 4095;
    const float4* xp = (const float4*)x;
    outx[id] = xp[((size_t)((b << 12) + src) << 5) + lane];
}

extern "C" void kernel_launch(void* const* d_in, const int* in_sizes, int n_in,
                              void* d_out, int out_size, void* d_ws, size_t ws_size,
                              hipStream_t stream) {
    const float* x  = (const float*)d_in[0];    // (8, 4096, 128) f32
    const float* rm = (const float*)d_in[1];    // (16, 64, 128) f32
    float* out = (float*)d_out;
    uint16_t* hws = (uint16_t*)d_ws;            // 512 KB: hashes, then inv in-place

    khash<<<dim3(ROWS_BL / 256, R_), 256, 0, stream>>>(x, rm, hws);
    ksort<<<dim3(R_ * B_), 256, 0, stream>>>(hws, out);
    kgather<<<dim3((XS_ELEMS / 4) / 256), 256, 0, stream>>>(x, hws, (float4*)out);
}